// Round 1
// baseline (6851.117 us; speedup 1.0000x reference)
//
#include <hip/hip_runtime.h>
#include <math.h>

#define HH 512      // hidden
#define BB 256      // batch
#define NK 128      // noise dim

__device__ __forceinline__ float lrelu(float x){ return x >= 0.f ? x : 0.2f*x; }
__device__ __forceinline__ float sigm(float x){ return 1.f/(1.f+expf(-x)); }

// block-wide sum over 256 threads
__device__ __forceinline__ float blk_sum(float v, float* red){
  int t = threadIdx.x;
  red[t] = v; __syncthreads();
  #pragma unroll
  for (int s = 128; s > 0; s >>= 1){
    if (t < s) red[t] += red[t+s];
    __syncthreads();
  }
  float r = red[0]; __syncthreads();
  return r;
}

// ---------------------------------------------------------------------------
// init: z0 = bn1(lrelu(z @ z2h_w^T + b)); h0 = z0; sz0 = bn2-half2(z0); prev=SOS
// grid: 512 blocks (one per hidden column), 256 threads (one per batch row)
// ---------------------------------------------------------------------------
__global__ __launch_bounds__(256) void k_init(
    const float* __restrict__ z, const float* __restrict__ w, const float* __restrict__ bz,
    const float* __restrict__ g1, const float* __restrict__ b1,
    const float* __restrict__ g2, const float* __restrict__ b2,
    float* __restrict__ h0, float* __restrict__ sz0, int* __restrict__ prev, int sos)
{
  __shared__ float red[256];
  int j = blockIdx.x, i = threadIdx.x;
  const float4* zr = (const float4*)(z + i*NK);
  const float4* wr = (const float4*)(w + j*NK);
  float acc = bz[j];
  #pragma unroll 8
  for (int k = 0; k < NK/4; k++){
    float4 a = zr[k], b = wr[k];
    acc = fmaf(a.x, b.x, acc); acc = fmaf(a.y, b.y, acc);
    acc = fmaf(a.z, b.z, acc); acc = fmaf(a.w, b.w, acc);
  }
  float t = lrelu(acc);
  float mu  = blk_sum(t, red) * (1.f/BB);
  float d   = t - mu;
  float var = blk_sum(d*d, red) * (1.f/BB);
  float z0v = g1[j] * d / sqrtf(var + 1e-5f) + b1[j];
  h0[i*HH + j] = z0v;
  // bn2 for the z0 half (columns 512..1023 of the concat)
  float mu2  = blk_sum(z0v, red) * (1.f/BB);
  float d2   = z0v - mu2;
  float var2 = blk_sum(d2*d2, red) * (1.f/BB);
  sz0[i*HH + j] = g2[HH + j] * d2 / sqrtf(var2 + 1e-5f) + b2[HH + j];
  if (j == 0) prev[i] = sos;
}

// ---------------------------------------------------------------------------
// per-step: se = bn2-half1(lrelu(emb[prev]))     grid 512, block 256
// ---------------------------------------------------------------------------
__global__ __launch_bounds__(256) void k_embed(
    const int* __restrict__ prev, const float* __restrict__ emb,
    const float* __restrict__ g2, const float* __restrict__ b2,
    float* __restrict__ se)
{
  __shared__ float red[256];
  int j = blockIdx.x, i = threadIdx.x;
  float t = lrelu(emb[prev[i]*HH + j]);
  float mu  = blk_sum(t, red) * (1.f/BB);
  float d   = t - mu;
  float var = blk_sum(d*d, red) * (1.f/BB);
  se[i*HH + j] = g2[j] * d / sqrtf(var + 1e-5f) + b2[j];
}

// ---------------------------------------------------------------------------
// per-step: o = bn3(lrelu(h))                    grid 512, block 256
// ---------------------------------------------------------------------------
__global__ __launch_bounds__(256) void k_bn3(
    const float* __restrict__ h, const float* __restrict__ g3, const float* __restrict__ b3,
    float* __restrict__ o)
{
  __shared__ float red[256];
  int j = blockIdx.x, i = threadIdx.x;
  float t = lrelu(h[i*HH + j]);
  float mu  = blk_sum(t, red) * (1.f/BB);
  float d   = t - mu;
  float var = blk_sum(d*d, red) * (1.f/BB);
  o[i*HH + j] = g3[j] * d / sqrtf(var + 1e-5f) + b3[j];
}

// ---------------------------------------------------------------------------
// GRU: gi = se@We^T + gz0 (gz0 holds sz0@Wz^T + b_ih); gh = h@Whh^T + b_hh
// tile: 32 rows x 16 cols x 6 mats; grid (8,32), 256 threads
// ---------------------------------------------------------------------------
#define KT 64
__global__ __launch_bounds__(256) void k_gru(
    const float* __restrict__ se, const float* __restrict__ hcur,
    const float* __restrict__ wih, const float* __restrict__ whh,
    const float* __restrict__ gz0, const float* __restrict__ bhh,
    float* __restrict__ hnext)
{
  __shared__ float sA[2][32][68];   // [0]=se, [1]=h ; pad 68 avoids bank conflicts
  __shared__ float sB[6][16][68];   // [0..2]=wih gates r,z,n ; [3..5]=whh gates
  int m0 = blockIdx.x*32, kc0 = blockIdx.y*16;
  int tl = threadIdx.x;
  float accI[3][2] = {{0,0},{0,0},{0,0}};
  float accH[3][2] = {{0,0},{0,0},{0,0}};
  int c = tl & 15, r2 = (tl >> 4) * 2;

  for (int kt = 0; kt < HH; kt += KT){
    #pragma unroll
    for (int rep = 0; rep < 4; rep++){
      int f = tl + 256*rep;           // 0..1023
      int mat = f >> 9; int fi = f & 511;
      int row = fi >> 4; int kq = (fi & 15) * 4;
      const float* src = mat ? hcur : se;
      *(float4*)&sA[mat][row][kq] = *(const float4*)&src[(m0+row)*HH + kt + kq];
    }
    #pragma unroll
    for (int rep = 0; rep < 6; rep++){
      int f = tl + 256*rep;           // 0..1535
      int m6 = f >> 8; int fi = f & 255;
      int row = fi >> 4; int kq = (fi & 15) * 4;
      int gate = (m6 < 3) ? m6 : m6 - 3;
      int n = gate*HH + kc0 + row;
      float4 v;
      if (m6 < 3) v = *(const float4*)&wih[n*1024 + kt + kq];
      else        v = *(const float4*)&whh[n*HH   + kt + kq];
      *(float4*)&sB[m6][row][kq] = v;
    }
    __syncthreads();
    #pragma unroll
    for (int kk = 0; kk < KT; kk += 4){
      float4 a0 = *(const float4*)&sA[0][r2  ][kk];
      float4 a1 = *(const float4*)&sA[0][r2+1][kk];
      float4 h0v = *(const float4*)&sA[1][r2  ][kk];
      float4 h1v = *(const float4*)&sA[1][r2+1][kk];
      #pragma unroll
      for (int g = 0; g < 3; g++){
        float4 we = *(const float4*)&sB[g][c][kk];
        accI[g][0] = fmaf(a0.x,we.x, fmaf(a0.y,we.y, fmaf(a0.z,we.z, fmaf(a0.w,we.w, accI[g][0]))));
        accI[g][1] = fmaf(a1.x,we.x, fmaf(a1.y,we.y, fmaf(a1.z,we.z, fmaf(a1.w,we.w, accI[g][1]))));
        float4 wh = *(const float4*)&sB[3+g][c][kk];
        accH[g][0] = fmaf(h0v.x,wh.x, fmaf(h0v.y,wh.y, fmaf(h0v.z,wh.z, fmaf(h0v.w,wh.w, accH[g][0]))));
        accH[g][1] = fmaf(h1v.x,wh.x, fmaf(h1v.y,wh.y, fmaf(h1v.z,wh.z, fmaf(h1v.w,wh.w, accH[g][1]))));
      }
    }
    __syncthreads();
  }
  int k = kc0 + c;
  #pragma unroll
  for (int r = 0; r < 2; r++){
    int i = m0 + r2 + r;
    float gir = accI[0][r] + gz0[i*1536 + k];
    float giz = accI[1][r] + gz0[i*1536 + 512 + k];
    float gin = accI[2][r] + gz0[i*1536 + 1024 + k];
    float ghr = accH[0][r] + bhh[k];
    float ghz = accH[1][r] + bhh[512 + k];
    float ghn = accH[2][r] + bhh[1024 + k];
    float rg = sigm(gir + ghr);
    float zg = sigm(giz + ghz);
    float ng = tanhf(gin + rg*ghn);
    float hv = hcur[i*HH + k];
    hnext[i*HH + k] = (1.f - zg)*ng + zg*hv;
  }
}

// ---------------------------------------------------------------------------
// generic GEMM: out[i][n] = A[i,:]·Bm[n,:] + bias[n]; mode1 fuses gumbel+1/T
// tile 32x64, KT=64, 256 threads; thread: 4 rows x cols {c1, c1+32}
// ---------------------------------------------------------------------------
__global__ __launch_bounds__(256) void k_mm(
    const float* __restrict__ A, int lda,
    const float* __restrict__ Bm, int ldb,
    const float* __restrict__ bias, int N,
    float* __restrict__ out, int ldc,
    int mode,
    const float* __restrict__ gum, int ldg,
    const float* __restrict__ temp)
{
  __shared__ float sA[32][68];
  __shared__ float sB[64][68];
  int m0 = blockIdx.x*32, n0 = blockIdx.y*64;
  int tl = threadIdx.x;
  float acc[4][2] = {{0,0},{0,0},{0,0},{0,0}};
  int c1 = tl & 31, r4 = (tl >> 5) * 4;

  for (int kt = 0; kt < HH; kt += 64){
    #pragma unroll
    for (int rep = 0; rep < 2; rep++){
      int f = tl + 256*rep; int row = f >> 4; int kq = (f & 15) * 4;
      *(float4*)&sA[row][kq] = *(const float4*)&A[(m0+row)*lda + kt + kq];
    }
    #pragma unroll
    for (int rep = 0; rep < 4; rep++){
      int f = tl + 256*rep; int row = f >> 4; int kq = (f & 15) * 4;
      float4 v = make_float4(0.f,0.f,0.f,0.f);
      if (n0 + row < N) v = *(const float4*)&Bm[(n0+row)*ldb + kt + kq];
      *(float4*)&sB[row][kq] = v;
    }
    __syncthreads();
    #pragma unroll
    for (int kk = 0; kk < 64; kk += 4){
      float4 b0 = *(const float4*)&sB[c1     ][kk];
      float4 b1 = *(const float4*)&sB[c1 + 32][kk];
      #pragma unroll
      for (int r = 0; r < 4; r++){
        float4 a = *(const float4*)&sA[r4+r][kk];
        acc[r][0] = fmaf(a.x,b0.x, fmaf(a.y,b0.y, fmaf(a.z,b0.z, fmaf(a.w,b0.w, acc[r][0]))));
        acc[r][1] = fmaf(a.x,b1.x, fmaf(a.y,b1.y, fmaf(a.z,b1.z, fmaf(a.w,b1.w, acc[r][1]))));
      }
    }
    __syncthreads();
  }

  if (mode == 0){
    #pragma unroll
    for (int r = 0; r < 4; r++)
      #pragma unroll
      for (int j = 0; j < 2; j++){
        int v = n0 + c1 + 32*j;
        if (v < N) out[(m0+r4+r)*ldc + v] = acc[r][j] + bias[v];
      }
  } else {
    float tv = temp[0];
    #pragma unroll
    for (int r = 0; r < 4; r++)
      #pragma unroll
      for (int j = 0; j < 2; j++){
        int v = n0 + c1 + 32*j;
        if (v < N){
          int i = m0 + r4 + r;
          float u = gum[i*ldg + v];
          float g = -logf(-logf(u + 1e-20f) + 1e-20f);
          out[i*ldc + v] = (acc[r][j] + bias[v] + g) / tv;
        }
      }
  }
}

// ---------------------------------------------------------------------------
// softmax (in place over s written by k_mm mode1) + argmax -> prev
// grid BB blocks (one per row), 256 threads
// ---------------------------------------------------------------------------
__global__ __launch_bounds__(256) void k_softmax(
    float* __restrict__ outrow, int ldc, int V, int* __restrict__ prev)
{
  __shared__ float sbuf[5000];
  __shared__ float rmax[256];
  __shared__ int   ridx[256];
  __shared__ float rsum[256];
  int i = blockIdx.x, t = threadIdx.x;
  float* row = outrow + (long)i*ldc;
  float bm = -3.4e38f; int bi = 0;
  for (int v = t; v < V; v += 256){
    float s = row[v]; sbuf[v] = s;
    if (s > bm){ bm = s; bi = v; }
  }
  rmax[t] = bm; ridx[t] = bi; __syncthreads();
  for (int s = 128; s > 0; s >>= 1){
    if (t < s){
      float mv = rmax[t+s]; int mi = ridx[t+s];
      if (mv > rmax[t] || (mv == rmax[t] && mi < ridx[t])){ rmax[t] = mv; ridx[t] = mi; }
    }
    __syncthreads();
  }
  float m = rmax[0];
  float ls = 0.f;
  for (int v = t; v < V; v += 256){
    float p = expf(sbuf[v] - m); sbuf[v] = p; ls += p;
  }
  rsum[t] = ls; __syncthreads();
  for (int s = 128; s > 0; s >>= 1){
    if (t < s) rsum[t] += rsum[t+s];
    __syncthreads();
  }
  float inv = 1.f / rsum[0];
  for (int v = t; v < V; v += 256) row[v] = sbuf[v] * inv;
  if (t == 0) prev[i] = ridx[0];
}

// ---------------------------------------------------------------------------
extern "C" void kernel_launch(void* const* d_in, const int* in_sizes, int n_in,
                              void* d_out, int out_size, void* d_ws, size_t ws_size,
                              hipStream_t stream)
{
  const float* z     = (const float*)d_in[0];
  const float* z2h_w = (const float*)d_in[1];
  const float* z2h_b = (const float*)d_in[2];
  const float* emb   = (const float*)d_in[3];
  const float* bn1_g = (const float*)d_in[4];
  const float* bn1_b = (const float*)d_in[5];
  const float* bn2_g = (const float*)d_in[6];
  const float* bn2_b = (const float*)d_in[7];
  const float* bn3_g = (const float*)d_in[8];
  const float* bn3_b = (const float*)d_in[9];
  const float* wih   = (const float*)d_in[10];
  const float* whh   = (const float*)d_in[11];
  const float* bih   = (const float*)d_in[12];
  const float* bhh   = (const float*)d_in[13];
  const float* h2o_w = (const float*)d_in[14];
  const float* h2o_b = (const float*)d_in[15];
  const float* gum   = (const float*)d_in[16];
  const float* temp  = (const float*)d_in[18];
  float* out = (float*)d_out;

  int V = in_sizes[15];                 // vocab (h2o_b)
  int steps = out_size / (BB * V);

  char* ws = (char*)d_ws;
  float* sz0 = (float*)ws;  ws += (size_t)BB*HH*4;
  float* gz0 = (float*)ws;  ws += (size_t)BB*3*HH*4;
  float* se  = (float*)ws;  ws += (size_t)BB*HH*4;
  float* hb0 = (float*)ws;  ws += (size_t)BB*HH*4;
  float* hb1 = (float*)ws;  ws += (size_t)BB*HH*4;
  float* ob  = (float*)ws;  ws += (size_t)BB*HH*4;
  int*   prev = (int*)ws;

  k_init<<<HH, 256, 0, stream>>>(z, z2h_w, z2h_b, bn1_g, bn1_b, bn2_g, bn2_b,
                                 hb0, sz0, prev, V - 1);
  // gz0 = sz0 @ Wz^T + b_ih   (Wz = wih[:, 512:], row stride 1024)
  k_mm<<<dim3(BB/32, (3*HH)/64), 256, 0, stream>>>(
      sz0, HH, wih + HH, 2*HH, bih, 3*HH, gz0, 3*HH, 0, nullptr, 0, nullptr);

  for (int t = 0; t < steps; t++){
    const float* hc = (t & 1) ? hb1 : hb0;
    float*       hn = (t & 1) ? hb0 : hb1;
    k_embed<<<HH, 256, 0, stream>>>(prev, emb, bn2_g, bn2_b, se);
    k_gru<<<dim3(BB/32, HH/16), 256, 0, stream>>>(se, hc, wih, whh, gz0, bhh, hn);
    k_bn3<<<HH, 256, 0, stream>>>(hn, bn3_g, bn3_b, ob);
    k_mm<<<dim3(BB/32, (V + 63)/64), 256, 0, stream>>>(
        ob, HH, h2o_w, HH, h2o_b, V,
        out + (size_t)t*V, steps*V, 1, gum + (size_t)t*BB*V, V, temp);
    k_softmax<<<BB, 256, 0, stream>>>(out + (size_t)t*V, steps*V, V, prev);
  }
}